// Round 9
// baseline (1442.182 us; speedup 1.0000x reference)
//
#include <hip/hip_runtime.h>

// Problem: BiLSTM-CRF tagger NLL (forward only).
// B=64, L=128, E=300, H=256 (per dir), 4H=1024, T=64, V=50000.
// Output: single f32 scalar = mean(log_z - numerator).
//
// ws layout (float units):
//   XP_OFF   = 0           : xp[2][8192][1024]   (input projections, biases folded)
//   LSTM_OFF = 16777216    : lstm_out[8192][512] (cols 0-255 fwd h, 256-511 bwd h)
//   EM_OFF   = 20971520    : emissions[8192][64]
//   WBF_OFF  = 21495808    : w_hh fp8, wave-coalesced uint4 layout (512 KB)
//   NLL_OFF  = 21757952    : per-batch nll [64]
//
// Round 2-5: backend spills loop-invariant VGPR arrays across barriered loops.
// Round 6: per-thread-contiguous loads = 64 lines/wave-instr -> TA-bound.
// Round 7/8: 1 batch/block is AI=2 FLOP/byte -> DS/L2 weight motion dominates
//            (410us, VALUBusy 32%).
// Round 9: 4 batches/block (32 blocks). Thread (unit r, k-quarter kq) computes
//          all 4 gates x 4 batches; weights streamed once per CU-step shared by
//          4 chains (AI x4); h bf16-packed in LDS; counted vmcnt(4) pipeline.

#define XP_OFF   0
#define LSTM_OFF 16777216
#define EM_OFF   20971520
#define WBF_OFF  21495808
#define NLL_OFF  21757952

typedef float v2f __attribute__((ext_vector_type(2)));
typedef unsigned v4u __attribute__((ext_vector_type(4)));

__device__ __forceinline__ float sigmf(float x) { return 1.f / (1.f + __expf(-x)); }
__device__ __forceinline__ float tanhfast(float x) {
    float t = __expf(2.f * x);
    return 1.f - 2.f / (t + 1.f);
}

// ---- fp8 e4m3fn encode (RNE), |x| <= 4.0 guaranteed by caller ----
__device__ __forceinline__ unsigned enc8(float x) {
    unsigned s = (__float_as_uint(x) >> 31) << 7;
    float a = fabsf(x);
    if (a >= 0.015625f) {                    // normal: 2^-6 .. 4.0
        int e; float m = frexpf(a, &e);      // a = m*2^e, m in [0.5,1)
        float q = rintf(m * 16.f);           // in [8,16]
        if (q >= 16.f) { q = 8.f; e += 1; }
        int E = e - 1 + 7;
        return s | (unsigned)(E << 3) | (unsigned)((int)q - 8);
    } else {                                 // denormal: multiples of 2^-9
        float q = rintf(a * 512.f);          // 0..8
        if (q >= 8.f) return s | (1u << 3);  // rounds up to 2^-6
        return s | (unsigned)(int)q;
    }
}

// ---- fp8 e4m3fn pair decode ----
__device__ __forceinline__ v2f dec2lo(unsigned v) {
#if __has_builtin(__builtin_amdgcn_cvt_pk_f32_fp8)
    return __builtin_amdgcn_cvt_pk_f32_fp8((int)v, false);
#else
    unsigned b0 = v & 0xffu, b1 = (v >> 8) & 0xffu;
    v2f r;
    r.x = __uint_as_float(((b0 & 0x80u) << 24) | ((b0 & 0x7fu) << 20)) * 1.3292279957849159e36f;
    r.y = __uint_as_float(((b1 & 0x80u) << 24) | ((b1 & 0x7fu) << 20)) * 1.3292279957849159e36f;
    return r;
#endif
}
__device__ __forceinline__ v2f dec2hi(unsigned v) {
#if __has_builtin(__builtin_amdgcn_cvt_pk_f32_fp8)
    return __builtin_amdgcn_cvt_pk_f32_fp8((int)v, true);
#else
    unsigned b0 = (v >> 16) & 0xffu, b1 = (v >> 24) & 0xffu;
    v2f r;
    r.x = __uint_as_float(((b0 & 0x80u) << 24) | ((b0 & 0x7fu) << 20)) * 1.3292279957849159e36f;
    r.y = __uint_as_float(((b1 & 0x80u) << 24) | ((b1 & 0x7fu) << 20)) * 1.3292279957849159e36f;
    return r;
#endif
}

// ---------------- K0: repack w_hh (f32 -> fp8 e4m3, scaled x64) ----------------
// uint4 index = ((dir*16 + w)*16 + q)*64 + ln, q = gate*4 + q4 (gate 0..3 =
// i,f,g,o; q4 = k-subchunk).  Thread t = w*64+ln -> r = t&255, kq = t>>8.
// dword i of uint4 covers k = kq*64 + q4*16 + i*4 .. +3 of row gate*256+r.
__global__ __launch_bounds__(256) void cvt_whh_fp8(
    const float* __restrict__ wf, const float* __restrict__ wb,
    unsigned int* __restrict__ out)
{
    int idx = blockIdx.x * 256 + threadIdx.x;   // dword index 0 .. 131071
    int i    = idx & 3;
    int ln   = (idx >> 2) & 63;
    int q    = (idx >> 8) & 15;
    int w    = (idx >> 12) & 15;
    int dir  = idx >> 16;
    const float* wsrc = dir ? wb : wf;
    int t = w * 64 + ln;
    int r = t & 255, kq = t >> 8;
    int gate = q >> 2, q4 = q & 3;
    int row = gate * 256 + r;
    int k0 = kq * 64 + q4 * 16 + i * 4;
    const float* src = wsrc + (size_t)row * 256 + k0;
    unsigned o = 0;
    #pragma unroll
    for (int j = 0; j < 4; ++j) o |= enc8(src[j] * 64.f) << (8 * j);
    out[idx] = o;
}

// ---------------- K1: fused gather + input projection GEMM ----------------
// xp[dir][m][n] = emb[sent[m]] . w_ih_dir[n] + b_ih[n] + b_hh[n]
// M=8192, N=2048 (2 dirs x 1024), K=300.  BM=BN=128, BK=60.
__global__ __launch_bounds__(256) void xp_gemm(
    const int* __restrict__ sent, const float* __restrict__ emb,
    const float* __restrict__ w_ih_f, const float* __restrict__ b_ih_f, const float* __restrict__ b_hh_f,
    const float* __restrict__ w_ih_b, const float* __restrict__ b_ih_b, const float* __restrict__ b_hh_b,
    float* __restrict__ xp)
{
    __shared__ float as[60][128];
    __shared__ float bs[60][128];
    __shared__ int sidx[128];
    const int tid = threadIdx.x;
    const int m0 = blockIdx.x * 128;
    const int nt = blockIdx.y;
    const int dir = nt >> 3;
    const int n0 = (nt & 7) * 128;
    const float* w_ih = dir ? w_ih_b : w_ih_f;
    const float* bi = dir ? b_ih_b : b_ih_f;
    const float* bh = dir ? b_hh_b : b_hh_f;
    if (tid < 128) sidx[tid] = sent[m0 + tid];
    __syncthreads();
    const int lr = tid >> 1;
    const int lh = tid & 1;
    const int rb = (tid & 15) * 4;
    const int cb = (tid >> 4) * 4;
    float acc[8][8] = {};
    const float* asrc = emb  + (size_t)sidx[lr] * 300 + lh * 30;
    const float* bsrc = w_ih + (size_t)(n0 + lr) * 300 + lh * 30;
    for (int kc = 0; kc < 5; ++kc) {
        #pragma unroll
        for (int i = 0; i < 15; ++i) {
            float2 va = *(const float2*)(asrc + 2 * i);
            as[lh * 30 + 2 * i][lr]     = va.x;
            as[lh * 30 + 2 * i + 1][lr] = va.y;
            float2 vb = *(const float2*)(bsrc + 2 * i);
            bs[lh * 30 + 2 * i][lr]     = vb.x;
            bs[lh * 30 + 2 * i + 1][lr] = vb.y;
        }
        asrc += 60; bsrc += 60;
        __syncthreads();
        #pragma unroll 4
        for (int kk = 0; kk < 60; ++kk) {
            float a[8], b[8];
            *(float4*)(a)     = *(const float4*)&as[kk][rb];
            *(float4*)(a + 4) = *(const float4*)&as[kk][64 + rb];
            *(float4*)(b)     = *(const float4*)&bs[kk][cb];
            *(float4*)(b + 4) = *(const float4*)&bs[kk][64 + cb];
            #pragma unroll
            for (int i = 0; i < 8; ++i)
                #pragma unroll
                for (int jj = 0; jj < 8; ++jj)
                    acc[i][jj] += a[i] * b[jj];
        }
        __syncthreads();
    }
    float bias[8];
    #pragma unroll
    for (int jj = 0; jj < 4; ++jj) {
        bias[jj]     = bi[n0 + cb + jj]      + bh[n0 + cb + jj];
        bias[4 + jj] = bi[n0 + 64 + cb + jj] + bh[n0 + 64 + cb + jj];
    }
    float* outp = xp + (size_t)dir * 8388608 + (size_t)m0 * 1024 + n0;
    #pragma unroll
    for (int i = 0; i < 8; ++i) {
        int r = (i < 4) ? (rb + i) : (64 + rb + i - 4);
        float4 o0 = make_float4(acc[i][0] + bias[0], acc[i][1] + bias[1],
                                acc[i][2] + bias[2], acc[i][3] + bias[3]);
        float4 o1 = make_float4(acc[i][4] + bias[4], acc[i][5] + bias[5],
                                acc[i][6] + bias[6], acc[i][7] + bias[7]);
        *(float4*)&outp[(size_t)r * 1024 + cb]      = o0;
        *(float4*)&outp[(size_t)r * 1024 + 64 + cb] = o1;
    }
}

// ---------------- K2: LSTM recurrence, 4 batches per block ----------------
// 32 blocks = dir(2) x batch-group(16).  1024 threads.
// MAC role:   thread t -> unit r = t&255, k-quarter kq = t>>8; computes all
//             4 gates x 4 batches over k in [kq*64, kq*64+64).
// Activation: thread t -> unit r = t&255, batch ab = t>>8; holds c state.
// Weights streamed from L2 each step (shared by 4 batches), 16 asm LDG/wave
// in a 4-subchunk pipeline with counted vmcnt(4).  h bf16-packed in LDS.
__global__ __launch_bounds__(1024) void lstm_rec(
    const float* __restrict__ xp, const unsigned int* __restrict__ w8,
    float* __restrict__ lstm_out)
{
    const int bid = blockIdx.x;
    const int dir = bid >> 4;
    const int bg  = bid & 15;
    const int t  = threadIdx.x;
    const int w  = t >> 6;
    const int ln = t & 63;
    const int r  = t & 255;
    const int kq = t >> 8;
    const int ab = t >> 8;

    __shared__ __align__(16) unsigned short hs[4][256];   // h bf16 [batch][unit]
    __shared__ float part[4][4][4][256];                  // [kq][gate][batch][unit]

    const v4u* bA = (const v4u*)w8 + ((size_t)(dir * 16 + w) * 16 + 4)  * 64 + ln;
    const v4u* bB = (const v4u*)w8 + ((size_t)(dir * 16 + w) * 16 + 12) * 64 + ln;
    const v4u* hv = (const v4u*)hs;          // [batch][32] uint4

    const float* xpb = xp + (size_t)dir * 8388608 + (size_t)(bg * 4 + ab) * 131072;
    float* lob = lstm_out + (size_t)(bg * 4 + ab) * 128 * 512 + dir * 256 + r;

    float c = 0.f;
    hs[ab][r] = 0;
    const int dl = dir ? -1 : 1;
    int l = dir ? 127 : 0;
    const float* xf = xpb + (size_t)l * 1024;
    float x0 = xf[r], x1 = xf[256 + r], x2 = xf[512 + r], x3 = xf[768 + r];
    __syncthreads();

#define LDG1(reg, base, off) asm volatile("global_load_dwordx4 %0, %1, off offset:" off \
                                          : "=v"(reg) : "v"(base))
#define WAITV(N) { asm volatile("s_waitcnt vmcnt(" #N ")" ::: "memory"); \
                   __builtin_amdgcn_sched_barrier(0); }
#define UNP(hp, d) { hp.x = __uint_as_float((unsigned)(d) << 16); \
                     hp.y = __uint_as_float((unsigned)(d) & 0xffff0000u); }
#define PJ4(J, WI, WF, WG, WO, A0, B0, A1, B1, A2, B2, A3, B3) { \
    v2f wi0 = dec2lo(WI[J]), wi1 = dec2hi(WI[J]); \
    v2f wf0 = dec2lo(WF[J]), wf1 = dec2hi(WF[J]); \
    v2f wg0 = dec2lo(WG[J]), wg1 = dec2hi(WG[J]); \
    v2f wo0 = dec2lo(WO[J]), wo1 = dec2hi(WO[J]); \
    v2f hp0, hp1; \
    UNP(hp0, A0) UNP(hp1, B0) \
    ai0 += wi0*hp0; ai0 += wi1*hp1; af0 += wf0*hp0; af0 += wf1*hp1; \
    ag0 += wg0*hp0; ag0 += wg1*hp1; ao0 += wo0*hp0; ao0 += wo1*hp1; \
    UNP(hp0, A1) UNP(hp1, B1) \
    ai1 += wi0*hp0; ai1 += wi1*hp1; af1 += wf0*hp0; af1 += wf1*hp1; \
    ag1 += wg0*hp0; ag1 += wg1*hp1; ao1 += wo0*hp0; ao1 += wo1*hp1; \
    UNP(hp0, A2) UNP(hp1, B2) \
    ai2 += wi0*hp0; ai2 += wi1*hp1; af2 += wf0*hp0; af2 += wf1*hp1; \
    ag2 += wg0*hp0; ag2 += wg1*hp1; ao2 += wo0*hp0; ao2 += wo1*hp1; \
    UNP(hp0, A3) UNP(hp1, B3) \
    ai3 += wi0*hp0; ai3 += wi1*hp1; af3 += wf0*hp0; af3 += wf1*hp1; \
    ag3 += wg0*hp0; ag3 += wg1*hp1; ao3 += wo0*hp0; ao3 += wo1*hp1; }
#define PROC(SC, WI, WF, WG, WO) { \
    v4u h0 = hv[0 * 32 + kq * 8 + SC * 2], h1 = hv[1 * 32 + kq * 8 + SC * 2]; \
    v4u h2 = hv[2 * 32 + kq * 8 + SC * 2], h3 = hv[3 * 32 + kq * 8 + SC * 2]; \
    PJ4(0, WI, WF, WG, WO, h0[0], h0[1], h1[0], h1[1], h2[0], h2[1], h3[0], h3[1]) \
    PJ4(1, WI, WF, WG, WO, h0[2], h0[3], h1[2], h1[3], h2[2], h2[3], h3[2], h3[3]) \
    h0 = hv[0 * 32 + kq * 8 + SC * 2 + 1]; h1 = hv[1 * 32 + kq * 8 + SC * 2 + 1]; \
    h2 = hv[2 * 32 + kq * 8 + SC * 2 + 1]; h3 = hv[3 * 32 + kq * 8 + SC * 2 + 1]; \
    PJ4(2, WI, WF, WG, WO, h0[0], h0[1], h1[0], h1[1], h2[0], h2[1], h3[0], h3[1]) \
    PJ4(3, WI, WF, WG, WO, h0[2], h0[3], h1[2], h1[3], h2[2], h2[3], h3[2], h3[3]) }

    for (int s = 0; s < 128; ++s) {
        v2f ai0={0,0}, ai1={0,0}, ai2={0,0}, ai3={0,0};
        v2f af0={0,0}, af1={0,0}, af2={0,0}, af3={0,0};
        v2f ag0={0,0}, ag1={0,0}, ag2={0,0}, ag3={0,0};
        v2f ao0={0,0}, ao1={0,0}, ao2={0,0}, ao3={0,0};
        v4u aI, aF, aG, aO, bI, bF, bG, bO;
        // subchunk 0 + 1 issue (gates i,f from bA; g,o from bB)
        LDG1(aI, bA, "-4096"); LDG1(aF, bA, "0");
        LDG1(aG, bB, "-4096"); LDG1(aO, bB, "0");
        LDG1(bI, bA, "-3072"); LDG1(bF, bA, "1024");
        LDG1(bG, bB, "-3072"); LDG1(bO, bB, "1024");
        WAITV(4); PROC(0, aI, aF, aG, aO)
        LDG1(aI, bA, "-2048"); LDG1(aF, bA, "2048");
        LDG1(aG, bB, "-2048"); LDG1(aO, bB, "2048");
        WAITV(4); PROC(1, bI, bF, bG, bO)
        LDG1(bI, bA, "-1024"); LDG1(bF, bA, "3072");
        LDG1(bG, bB, "-1024"); LDG1(bO, bB, "3072");
        WAITV(4); PROC(2, aI, aF, aG, aO)
        WAITV(0); PROC(3, bI, bF, bG, bO)

        // prefetch next step's xp (issued after all weight vmcnt accounting)
        const float* xn = xpb + (size_t)(l + dl) * 1024;
        float nx0 = xn[r], nx1 = xn[256 + r], nx2 = xn[512 + r], nx3 = xn[768 + r];

        part[kq][0][0][r] = ai0.x + ai0.y; part[kq][0][1][r] = ai1.x + ai1.y;
        part[kq][0][2][r] = ai2.x + ai2.y; part[kq][0][3][r] = ai3.x + ai3.y;
        part[kq][1][0][r] = af0.x + af0.y; part[kq][1][1][r] = af1.x + af1.y;
        part[kq][1][2][r] = af2.x + af2.y; part[kq][1][3][r] = af3.x + af3.y;
        part[kq][2][0][r] = ag0.x + ag0.y; part[kq][2][1][r] = ag1.x + ag1.y;
        part[kq][2][2][r] = ag2.x + ag2.y; part[kq][2][3][r] = ag3.x + ag3.y;
        part[kq][3][0][r] = ao0.x + ao0.y; part[kq][3][1][r] = ao1.x + ao1.y;
        part[kq][3][2][r] = ao2.x + ao2.y; part[kq][3][3][r] = ao3.x + ao3.y;
        __syncthreads();
        {
            float si = part[0][0][ab][r] + part[1][0][ab][r] + part[2][0][ab][r] + part[3][0][ab][r];
            float sf = part[0][1][ab][r] + part[1][1][ab][r] + part[2][1][ab][r] + part[3][1][ab][r];
            float sg = part[0][2][ab][r] + part[1][2][ab][r] + part[2][2][ab][r] + part[3][2][ab][r];
            float so = part[0][3][ab][r] + part[1][3][ab][r] + part[2][3][ab][r] + part[3][3][ab][r];
            float gi = fmaf(si, 0.015625f, x0);    // /64 undoes encode scale
            float gf = fmaf(sf, 0.015625f, x1);
            float gg = fmaf(sg, 0.015625f, x2);
            float go = fmaf(so, 0.015625f, x3);
            c = sigmf(gf) * c + sigmf(gi) * tanhfast(gg);
            float h = sigmf(go) * tanhfast(c);
            lob[(size_t)l * 512] = h;
            unsigned u = __float_as_uint(h);       // f32 -> bf16 RNE
            hs[ab][r] = (unsigned short)((u + 0x7fffu + ((u >> 16) & 1u)) >> 16);
        }
        __syncthreads();
        x0 = nx0; x1 = nx1; x2 = nx2; x3 = nx3;
        l += dl;
    }
#undef LDG1
#undef WAITV
#undef UNP
#undef PJ4
#undef PROC
}

// ---------------- K3: emissions GEMM ----------------
__global__ __launch_bounds__(256) void emis_gemm(
    const float* __restrict__ lo, const float* __restrict__ w_out,
    const float* __restrict__ b_out, float* __restrict__ em)
{
    __shared__ float as[64][64];
    __shared__ float bs[64][64];
    const int tid = threadIdx.x;
    const int m0 = blockIdx.x * 64;
    const int mr = tid & 63;
    const int kq = tid >> 6;
    const int rb = (tid & 15) * 4;
    const int cb = (tid >> 4) * 4;
    float acc[4][4] = {};
    for (int kc = 0; kc < 8; ++kc) {
        const int k0 = kc * 64;
        #pragma unroll
        for (int i = 0; i < 4; ++i) {
            const int k = kq * 16 + 4 * i;
            float4 va = *(const float4*)&lo[(size_t)(m0 + mr) * 512 + k0 + k];
            as[k][mr] = va.x; as[k + 1][mr] = va.y; as[k + 2][mr] = va.z; as[k + 3][mr] = va.w;
            float4 vb = *(const float4*)&w_out[(size_t)mr * 512 + k0 + k];
            bs[k][mr] = vb.x; bs[k + 1][mr] = vb.y; bs[k + 2][mr] = vb.z; bs[k + 3][mr] = vb.w;
        }
        __syncthreads();
        #pragma unroll 8
        for (int kk = 0; kk < 64; ++kk) {
            float a[4], bb[4];
            *(float4*)a  = *(const float4*)&as[kk][rb];
            *(float4*)bb = *(const float4*)&bs[kk][cb];
            #pragma unroll
            for (int i = 0; i < 4; ++i)
                #pragma unroll
                for (int jj = 0; jj < 4; ++jj)
                    acc[i][jj] += a[i] * bb[jj];
        }
        __syncthreads();
    }
    float4 bo = *(const float4*)&b_out[cb];
    #pragma unroll
    for (int i = 0; i < 4; ++i) {
        float4 o = make_float4(acc[i][0] + bo.x, acc[i][1] + bo.y,
                               acc[i][2] + bo.z, acc[i][3] + bo.w);
        *(float4*)&em[(size_t)(m0 + rb + i) * 64 + cb] = o;
    }
}

// ---------------- K4: CRF numerator + forward algorithm ----------------
__global__ __launch_bounds__(256) void crf_kernel(
    const float* __restrict__ em, const int* __restrict__ tags,
    const float* __restrict__ start_t, const float* __restrict__ end_t,
    const float* __restrict__ trans, float* __restrict__ nll)
{
    const int b = blockIdx.x;
    const int tid = threadIdx.x;
    const int j = tid & 63;
    const int q = tid >> 6;
    __shared__ float s_lds[64];
    __shared__ float part[4][64];
    __shared__ float m_sh, num_sh;
    float tr[16];
    #pragma unroll
    for (int ii = 0; ii < 16; ++ii) tr[ii] = trans[(q * 16 + ii) * 64 + j];
    const float* emb_b = em + (size_t)b * 8192;
    const int* tg_b = tags + b * 128;
    float numpart = 0.f;
    if (tid < 128) {
        int l = tid;
        int tg = tg_b[l];
        numpart = emb_b[l * 64 + tg];
        if (l < 127) numpart += trans[tg * 64 + tg_b[l + 1]];
        if (l == 0)  numpart += start_t[tg];
        if (l == 127) numpart += end_t[tg];
    }
    float red = numpart;
    #pragma unroll
    for (int off = 32; off >= 1; off >>= 1) red += __shfl_xor(red, off);
    if (j == 0) part[q][0] = red;
    if (q == 0) s_lds[j] = start_t[j] + emb_b[j];
    __syncthreads();
    if (tid == 0) num_sh = part[0][0] + part[1][0] + part[2][0] + part[3][0];
    __syncthreads();
    for (int l = 1; l < 128; ++l) {
        if (q == 0) {
            float v = s_lds[j];
            #pragma unroll
            for (int off = 32; off >= 1; off >>= 1) v = fmaxf(v, __shfl_xor(v, off));
            if (j == 0) m_sh = v;
        }
        __syncthreads();
        const float m = m_sh;
        float sv[16];
        #pragma unroll
        for (int t4 = 0; t4 < 4; ++t4) {
            float4 v = *(const float4*)&s_lds[q * 16 + 4 * t4];
            sv[4 * t4] = v.x; sv[4 * t4 + 1] = v.y; sv[4 * t4 + 2] = v.z; sv[4 * t4 + 3] = v.w;
        }
        float acc = 0.f;
        #pragma unroll
        for (int ii = 0; ii < 16; ++ii) acc += __expf(sv[ii] + tr[ii] - m);
        part[q][j] = acc;
        __syncthreads();
        if (q == 0) {
            float t = part[0][j] + part[1][j] + part[2][j] + part[3][j];
            s_lds[j] = m + __logf(t) + emb_b[l * 64 + j];
        }
    }
    if (q == 0) {
        float v = s_lds[j] + end_t[j];
        float mm = v;
        #pragma unroll
        for (int off = 32; off >= 1; off >>= 1) mm = fmaxf(mm, __shfl_xor(mm, off));
        float e = __expf(v - mm);
        #pragma unroll
        for (int off = 32; off >= 1; off >>= 1) e += __shfl_xor(e, off);
        if (j == 0) nll[b] = (mm + __logf(e)) - num_sh;
    }
}

// ---------------- K5: final mean ----------------
__global__ void finalize(const float* __restrict__ nll, float* __restrict__ out)
{
    int j = threadIdx.x;
    float v = nll[j];
    #pragma unroll
    for (int off = 32; off >= 1; off >>= 1) v += __shfl_xor(v, off);
    if (j == 0) out[0] = v * (1.f / 64.f);
}

extern "C" void kernel_launch(void* const* d_in, const int* in_sizes, int n_in,
                              void* d_out, int out_size, void* d_ws, size_t ws_size,
                              hipStream_t stream) {
    const int* sent      = (const int*)d_in[0];
    const int* tags      = (const int*)d_in[1];
    const float* emb     = (const float*)d_in[2];
    const float* w_ih_f  = (const float*)d_in[3];
    const float* w_hh_f  = (const float*)d_in[4];
    const float* b_ih_f  = (const float*)d_in[5];
    const float* b_hh_f  = (const float*)d_in[6];
    const float* w_ih_b  = (const float*)d_in[7];
    const float* w_hh_b  = (const float*)d_in[8];
    const float* b_ih_b  = (const float*)d_in[9];
    const float* b_hh_b  = (const float*)d_in[10];
    const float* w_out   = (const float*)d_in[11];
    const float* b_out   = (const float*)d_in[12];
    const float* start_t = (const float*)d_in[13];
    const float* end_t   = (const float*)d_in[14];
    const float* trans   = (const float*)d_in[15];

    float* ws = (float*)d_ws;
    float* xp        = ws + XP_OFF;
    float* lstm_out  = ws + LSTM_OFF;
    float* em        = ws + EM_OFF;
    unsigned int* w8 = (unsigned int*)(ws + WBF_OFF);
    float* nll       = ws + NLL_OFF;

    cvt_whh_fp8<<<dim3(512), dim3(256), 0, stream>>>(w_hh_f, w_hh_b, w8);
    xp_gemm<<<dim3(64, 16), dim3(256), 0, stream>>>(sent, emb,
        w_ih_f, b_ih_f, b_hh_f, w_ih_b, b_ih_b, b_hh_b, xp);
    lstm_rec<<<dim3(32), dim3(1024), 0, stream>>>(xp, w8, lstm_out);
    emis_gemm<<<dim3(128), dim3(256), 0, stream>>>(lstm_out, w_out, b_out, em);
    crf_kernel<<<dim3(64), dim3(256), 0, stream>>>(em, tags, start_t, end_t, trans, nll);
    finalize<<<dim3(1), dim3(64), 0, stream>>>(nll, (float*)d_out);
}

// Round 10
// 602.358 us; speedup vs baseline: 2.3942x; 2.3942x over previous
//
#include <hip/hip_runtime.h>

// Problem: BiLSTM-CRF tagger NLL (forward only).
// B=64, L=128, E=300, H=256 (per dir), 4H=1024, T=64, V=50000.
// Output: single f32 scalar = mean(log_z - numerator).
//
// ws layout (float units):
//   XP_OFF   = 0           : xp[2][8192][1024]   (input projections, biases folded)
//   LSTM_OFF = 16777216    : lstm_out[8192][512] (cols 0-255 fwd h, 256-511 bwd h)
//   EM_OFF   = 20971520    : emissions[8192][64]
//   WBF_OFF  = 21495808    : w_hh fp8, wave-coalesced uint4 layout (512 KB)
//   NLL_OFF  = 21757952    : per-batch nll [64]
//
// Lessons: R2-5 backend spills loop-invariant VGPR arrays (stream instead).
// R6: per-thread-contiguous loads = 64 lines/wave-instr -> TA-bound.
// R7/8: per-subchunk lgkmcnt(0) stop-and-go -> DS/VALU serialization.
// R9: LDS < 80KB -> 2 blocks/CU feasible -> 64-VGPR cap -> spill. Keep LDS
//     >80KB (1 block/CU -> 128-VGPR budget) and c=1 chain/CU.
// R10: round-8 roles + software-pipelined inner loop: ds issues 1 subchunk
//      ahead (lgkmcnt(6)), streamed g/o under vmcnt(10/8/6/4), xp via asm
//      after weight LDGs, b128 part exchange.

#define XP_OFF   0
#define LSTM_OFF 16777216
#define EM_OFF   20971520
#define WBF_OFF  21495808
#define NLL_OFF  21757952

typedef float v2f __attribute__((ext_vector_type(2)));
typedef float v4f __attribute__((ext_vector_type(4)));
typedef unsigned v4u __attribute__((ext_vector_type(4)));

__device__ __forceinline__ float sigmf(float x) { return 1.f / (1.f + __expf(-x)); }
__device__ __forceinline__ float tanhfast(float x) {
    float t = __expf(2.f * x);
    return 1.f - 2.f / (t + 1.f);
}

// ---- fp8 e4m3fn encode (RNE), |x| <= 4.0 guaranteed by caller ----
__device__ __forceinline__ unsigned enc8(float x) {
    unsigned s = (__float_as_uint(x) >> 31) << 7;
    float a = fabsf(x);
    if (a >= 0.015625f) {                    // normal: 2^-6 .. 4.0
        int e; float m = frexpf(a, &e);      // a = m*2^e, m in [0.5,1)
        float q = rintf(m * 16.f);           // in [8,16]
        if (q >= 16.f) { q = 8.f; e += 1; }
        int E = e - 1 + 7;
        return s | (unsigned)(E << 3) | (unsigned)((int)q - 8);
    } else {                                 // denormal: multiples of 2^-9
        float q = rintf(a * 512.f);          // 0..8
        if (q >= 8.f) return s | (1u << 3);  // rounds up to 2^-6
        return s | (unsigned)(int)q;
    }
}

// ---- fp8 e4m3fn pair decode ----
__device__ __forceinline__ v2f dec2lo(unsigned v) {
#if __has_builtin(__builtin_amdgcn_cvt_pk_f32_fp8)
    return __builtin_amdgcn_cvt_pk_f32_fp8((int)v, false);
#else
    unsigned b0 = v & 0xffu, b1 = (v >> 8) & 0xffu;
    v2f r;
    r.x = __uint_as_float(((b0 & 0x80u) << 24) | ((b0 & 0x7fu) << 20)) * 1.3292279957849159e36f;
    r.y = __uint_as_float(((b1 & 0x80u) << 24) | ((b1 & 0x7fu) << 20)) * 1.3292279957849159e36f;
    return r;
#endif
}
__device__ __forceinline__ v2f dec2hi(unsigned v) {
#if __has_builtin(__builtin_amdgcn_cvt_pk_f32_fp8)
    return __builtin_amdgcn_cvt_pk_f32_fp8((int)v, true);
#else
    unsigned b0 = (v >> 16) & 0xffu, b1 = (v >> 24) & 0xffu;
    v2f r;
    r.x = __uint_as_float(((b0 & 0x80u) << 24) | ((b0 & 0x7fu) << 20)) * 1.3292279957849159e36f;
    r.y = __uint_as_float(((b1 & 0x80u) << 24) | ((b1 & 0x7fu) << 20)) * 1.3292279957849159e36f;
    return r;
#endif
}

// ---------------- K0: repack w_hh (f32 -> fp8 e4m3, scaled x64) ----------------
// uint4 index = half*16384 + ((dir*16 + w)*8 + q)*64 + ln   (half0=cached i,f;
// half1=streamed g,o).  Thread t=w*64+ln, r=t&255, kq=t>>8.
//   half0: gate = q>>2 (0=i,1=f), q4 = q&3
//   half1: gate = 2+(q&1) (2=g,3=o), q4 = q>>1
//   dword i covers k = kq*64 + q4*16 + i*4 .. +3 of row gate*256+r.
__global__ __launch_bounds__(256) void cvt_whh_fp8(
    const float* __restrict__ wf, const float* __restrict__ wb,
    unsigned int* __restrict__ out)
{
    int idx = blockIdx.x * 256 + threadIdx.x;   // dword index 0 .. 131071
    int i    = idx & 3;
    int ln   = (idx >> 2) & 63;
    int q    = (idx >> 8) & 7;
    int w    = (idx >> 11) & 15;
    int dir  = (idx >> 15) & 1;
    int half = (idx >> 16) & 1;
    const float* wsrc = dir ? wb : wf;
    int t = w * 64 + ln;
    int r = t & 255, kq = t >> 8;
    int g_, q4;
    if (half == 0) { g_ = q >> 2;       q4 = q & 3;  }
    else           { g_ = 2 + (q & 1);  q4 = q >> 1; }
    int row = g_ * 256 + r;
    int k0 = kq * 64 + q4 * 16 + i * 4;
    const float* src = wsrc + (size_t)row * 256 + k0;
    unsigned o = 0;
    #pragma unroll
    for (int j = 0; j < 4; ++j) o |= enc8(src[j] * 64.f) << (8 * j);
    out[idx] = o;
}

// ---------------- K1: fused gather + input projection GEMM ----------------
__global__ __launch_bounds__(256) void xp_gemm(
    const int* __restrict__ sent, const float* __restrict__ emb,
    const float* __restrict__ w_ih_f, const float* __restrict__ b_ih_f, const float* __restrict__ b_hh_f,
    const float* __restrict__ w_ih_b, const float* __restrict__ b_ih_b, const float* __restrict__ b_hh_b,
    float* __restrict__ xp)
{
    __shared__ float as[60][128];
    __shared__ float bs[60][128];
    __shared__ int sidx[128];
    const int tid = threadIdx.x;
    const int m0 = blockIdx.x * 128;
    const int nt = blockIdx.y;
    const int dir = nt >> 3;
    const int n0 = (nt & 7) * 128;
    const float* w_ih = dir ? w_ih_b : w_ih_f;
    const float* bi = dir ? b_ih_b : b_ih_f;
    const float* bh = dir ? b_hh_b : b_hh_f;
    if (tid < 128) sidx[tid] = sent[m0 + tid];
    __syncthreads();
    const int lr = tid >> 1;
    const int lh = tid & 1;
    const int rb = (tid & 15) * 4;
    const int cb = (tid >> 4) * 4;
    float acc[8][8] = {};
    const float* asrc = emb  + (size_t)sidx[lr] * 300 + lh * 30;
    const float* bsrc = w_ih + (size_t)(n0 + lr) * 300 + lh * 30;
    for (int kc = 0; kc < 5; ++kc) {
        #pragma unroll
        for (int i = 0; i < 15; ++i) {
            float2 va = *(const float2*)(asrc + 2 * i);
            as[lh * 30 + 2 * i][lr]     = va.x;
            as[lh * 30 + 2 * i + 1][lr] = va.y;
            float2 vb = *(const float2*)(bsrc + 2 * i);
            bs[lh * 30 + 2 * i][lr]     = vb.x;
            bs[lh * 30 + 2 * i + 1][lr] = vb.y;
        }
        asrc += 60; bsrc += 60;
        __syncthreads();
        #pragma unroll 4
        for (int kk = 0; kk < 60; ++kk) {
            float a[8], b[8];
            *(float4*)(a)     = *(const float4*)&as[kk][rb];
            *(float4*)(a + 4) = *(const float4*)&as[kk][64 + rb];
            *(float4*)(b)     = *(const float4*)&bs[kk][cb];
            *(float4*)(b + 4) = *(const float4*)&bs[kk][64 + cb];
            #pragma unroll
            for (int i = 0; i < 8; ++i)
                #pragma unroll
                for (int jj = 0; jj < 8; ++jj)
                    acc[i][jj] += a[i] * b[jj];
        }
        __syncthreads();
    }
    float bias[8];
    #pragma unroll
    for (int jj = 0; jj < 4; ++jj) {
        bias[jj]     = bi[n0 + cb + jj]      + bh[n0 + cb + jj];
        bias[4 + jj] = bi[n0 + 64 + cb + jj] + bh[n0 + 64 + cb + jj];
    }
    float* outp = xp + (size_t)dir * 8388608 + (size_t)m0 * 1024 + n0;
    #pragma unroll
    for (int i = 0; i < 8; ++i) {
        int r = (i < 4) ? (rb + i) : (64 + rb + i - 4);
        float4 o0 = make_float4(acc[i][0] + bias[0], acc[i][1] + bias[1],
                                acc[i][2] + bias[2], acc[i][3] + bias[3]);
        float4 o1 = make_float4(acc[i][4] + bias[4], acc[i][5] + bias[5],
                                acc[i][6] + bias[6], acc[i][7] + bias[7]);
        *(float4*)&outp[(size_t)r * 1024 + cb]      = o0;
        *(float4*)&outp[(size_t)r * 1024 + 64 + cb] = o1;
    }
}

// ---------------- K2: LSTM recurrence, pipelined ----------------
// 128 blocks = (dir, batch), XCD-aligned: dir = (bid&7)>>2.  1024 threads.
// Thread t: r=t&255 (unit), kq=t>>8 (k-quarter, uniform per wave). Owns all
// 4 gates of unit r over k in [kq*64, kq*64+64).
// i,f weights LDS-cached (128 KB); g,o streamed from L2; h f32 in LDS
// (uniform b128 broadcast); partials exchanged via b128 [kq][unit][gate].
// Pipeline: ds issues 1 subchunk ahead (lgkmcnt(6)); streamed under counted
// vmcnt (10/8/6/4, never 0 in MAC phase); xp asm-loaded after weight LDGs,
// consumed in act phase ~2500cy later.
__global__ __launch_bounds__(1024) void lstm_rec(
    const float* __restrict__ xp, const unsigned int* __restrict__ w8,
    float* __restrict__ lstm_out)
{
    const int bid = blockIdx.x;
    const int r8  = bid & 7;
    const int dir = r8 >> 2;
    const int b   = ((bid >> 3) << 2) | (r8 & 3);
    const int t  = threadIdx.x;
    const int w  = t >> 6;
    const int ln = t & 63;
    const int r  = t & 255;
    const int kq = t >> 8;
    __shared__ __align__(16) float hs[256];          // h f32 [unit]
    __shared__ __align__(16) float part2[4][256][4]; // [kq][unit][gate] 16 KB
    __shared__ v4u wl[8192];                         // 128 KB cached i,f
    // LDS total 145 KB -> 1 block/CU -> 128-VGPR allocator budget (R9 lesson)

    const v4u* w4 = (const v4u*)w8;
    #pragma unroll
    for (int q = 0; q < 8; ++q)
        wl[(w * 8 + q) * 64 + ln] = w4[((size_t)(dir * 16 + w) * 8 + q) * 64 + ln];

    // streamed half base at q=4 so byte offsets span -4096..+3072
    const v4u* sbase = w4 + 16384 + ((size_t)(dir * 16 + w) * 8 + 4) * 64 + ln;
    const unsigned wofs = (unsigned)(size_t)&wl[w * 512 + ln];
    const unsigned hofs = (unsigned)(size_t)&hs[kq * 64];
    float* lob = lstm_out + (size_t)b * 128 * 512 + dir * 256 + r;

    float c = 0.f;
    if (t < 256) hs[t] = 0.f;
    const float* xpb = xp + (size_t)dir * 8388608 + (size_t)b * 131072;
    const int dl = dir ? -1 : 1;
    int l = dir ? 127 : 0;
    __syncthreads();

#define LDG(reg, off) asm volatile("global_load_dwordx4 %0, %1, off offset:" off \
                                   : "=v"(reg) : "v"(sbase))
#define DSRH(reg, off) asm volatile("ds_read_b128 %0, %1 offset:" off \
                                    : "=v"(reg) : "v"(hofs))
#define DSRW(reg, off) asm volatile("ds_read_b128 %0, %1 offset:" off \
                                    : "=v"(reg) : "v"(wofs))
#define WAITL(N) { asm volatile("s_waitcnt lgkmcnt(" #N ")" ::: "memory"); \
                   __builtin_amdgcn_sched_barrier(0); }
#define WAITV(N) { asm volatile("s_waitcnt vmcnt(" #N ")" ::: "memory"); \
                   __builtin_amdgcn_sched_barrier(0); }
#define GMAC(acc0, acc1, w0, w1, h0, h1, h2, h3) { \
    v2f p01, p23; \
    p01.x = h0.x; p01.y = h0.y; p23.x = h0.z; p23.y = h0.w; \
    acc0 += dec2lo(w0[0]) * p01; acc0 += dec2hi(w0[0]) * p23; \
    acc1 += dec2lo(w1[0]) * p01; acc1 += dec2hi(w1[0]) * p23; \
    p01.x = h1.x; p01.y = h1.y; p23.x = h1.z; p23.y = h1.w; \
    acc0 += dec2lo(w0[1]) * p01; acc0 += dec2hi(w0[1]) * p23; \
    acc1 += dec2lo(w1[1]) * p01; acc1 += dec2hi(w1[1]) * p23; \
    p01.x = h2.x; p01.y = h2.y; p23.x = h2.z; p23.y = h2.w; \
    acc0 += dec2lo(w0[2]) * p01; acc0 += dec2hi(w0[2]) * p23; \
    acc1 += dec2lo(w1[2]) * p01; acc1 += dec2hi(w1[2]) * p23; \
    p01.x = h3.x; p01.y = h3.y; p23.x = h3.z; p23.y = h3.w; \
    acc0 += dec2lo(w0[3]) * p01; acc0 += dec2hi(w0[3]) * p23; \
    acc1 += dec2lo(w1[3]) * p01; acc1 += dec2hi(w1[3]) * p23; }

    for (int s = 0; s < 128; ++s) {
        // --- issue: 8 streamed g/o LDGs first (vmcnt oldest), then 4 xp ---
        v4u s0, s1, s2, s3, s4, s5, s6, s7;
        LDG(s0, "-4096"); LDG(s1, "-3072"); LDG(s2, "-2048"); LDG(s3, "-1024");
        LDG(s4, "0");     LDG(s5, "1024");  LDG(s6, "2048");  LDG(s7, "3072");
        float x0, x1, x2, x3;
        {
            const float* xcur = xpb + (size_t)l * 1024 + r;
            asm volatile("global_load_dword %0, %4, off\n\t"
                         "global_load_dword %1, %4, off offset:1024\n\t"
                         "global_load_dword %2, %4, off offset:2048\n\t"
                         "global_load_dword %3, %4, off offset:3072"
                         : "=v"(x0), "=v"(x1), "=v"(x2), "=v"(x3) : "v"(xcur));
        }
        // --- ds issues for sc0, sc1 (6 each: 4 h + ci + cf) ---
        v4f hA0, hA1, hA2, hA3, hB0, hB1, hB2, hB3;
        v4u cAi, cAf, cBi, cBf;
        DSRH(hA0, "0");   DSRH(hA1, "16");  DSRH(hA2, "32");  DSRH(hA3, "48");
        DSRW(cAi, "0");   DSRW(cAf, "4096");
        DSRH(hB0, "64");  DSRH(hB1, "80");  DSRH(hB2, "96");  DSRH(hB3, "112");
        DSRW(cBi, "1024"); DSRW(cBf, "5120");

        v2f ai = {0.f, 0.f}, af = {0.f, 0.f}, ag = {0.f, 0.f}, ao = {0.f, 0.f};
        // --- sc0 ---
        WAITL(6);
        GMAC(ai, af, cAi, cAf, hA0, hA1, hA2, hA3)
        WAITV(10);
        GMAC(ag, ao, s0, s1, hA0, hA1, hA2, hA3)
        // issue sc2
        DSRH(hA0, "128"); DSRH(hA1, "144"); DSRH(hA2, "160"); DSRH(hA3, "176");
        DSRW(cAi, "2048"); DSRW(cAf, "6144");
        // --- sc1 ---
        WAITL(6);
        GMAC(ai, af, cBi, cBf, hB0, hB1, hB2, hB3)
        WAITV(8);
        GMAC(ag, ao, s2, s3, hB0, hB1, hB2, hB3)
        // issue sc3
        DSRH(hB0, "192"); DSRH(hB1, "208"); DSRH(hB2, "224"); DSRH(hB3, "240");
        DSRW(cBi, "3072"); DSRW(cBf, "7168");
        // --- sc2 ---
        WAITL(6);
        GMAC(ai, af, cAi, cAf, hA0, hA1, hA2, hA3)
        WAITV(6);
        GMAC(ag, ao, s4, s5, hA0, hA1, hA2, hA3)
        // --- sc3 ---
        WAITL(0);
        GMAC(ai, af, cBi, cBf, hB0, hB1, hB2, hB3)
        WAITV(4);
        GMAC(ag, ao, s6, s7, hB0, hB1, hB2, hB3)

        // --- partial exchange: one b128 per thread, sequential addresses ---
        *(float4*)&part2[kq][r][0] =
            make_float4(ai.x + ai.y, af.x + af.y, ag.x + ag.y, ao.x + ao.y);
        __syncthreads();
        if (t < 256) {
            asm volatile("s_waitcnt vmcnt(0)" ::: "memory");
            __builtin_amdgcn_sched_barrier(0);
            float4 p0 = *(const float4*)&part2[0][t][0];
            float4 p1 = *(const float4*)&part2[1][t][0];
            float4 p2 = *(const float4*)&part2[2][t][0];
            float4 p3 = *(const float4*)&part2[3][t][0];
            float gi = fmaf(p0.x + p1.x + p2.x + p3.x, 0.015625f, x0);
            float gf = fmaf(p0.y + p1.y + p2.y + p3.y, 0.015625f, x1);
            float gg = fmaf(p0.z + p1.z + p2.z + p3.z, 0.015625f, x2);
            float go = fmaf(p0.w + p1.w + p2.w + p3.w, 0.015625f, x3);
            c = sigmf(gf) * c + sigmf(gi) * tanhfast(gg);
            float h = sigmf(go) * tanhfast(c);
            hs[t] = h;
            lob[(size_t)l * 512] = h;
        }
        __syncthreads();
        l += dl;
    }
#undef LDG
#undef DSRH
#undef DSRW
#undef WAITL
#undef WAITV
#undef GMAC
}

// ---------------- K3: emissions GEMM ----------------
__global__ __launch_bounds__(256) void emis_gemm(
    const float* __restrict__ lo, const float* __restrict__ w_out,
    const float* __restrict__ b_out, float* __restrict__ em)
{
    __shared__ float as[64][64];
    __shared__ float bs[64][64];
    const int tid = threadIdx.x;
    const int m0 = blockIdx.x * 64;
    const int mr = tid & 63;
    const int kq = tid >> 6;
    const int rb = (tid & 15) * 4;
    const int cb = (tid >> 4) * 4;
    float acc[4][4] = {};
    for (int kc = 0; kc < 8; ++kc) {
        const int k0 = kc * 64;
        #pragma unroll
        for (int i = 0; i < 4; ++i) {
            const int k = kq * 16 + 4 * i;
            float4 va = *(const float4*)&lo[(size_t)(m0 + mr) * 512 + k0 + k];
            as[k][mr] = va.x; as[k + 1][mr] = va.y; as[k + 2][mr] = va.z; as[k + 3][mr] = va.w;
            float4 vb = *(const float4*)&w_out[(size_t)mr * 512 + k0 + k];
            bs[k][mr] = vb.x; bs[k + 1][mr] = vb.y; bs[k + 2][mr] = vb.z; bs[k + 3][mr] = vb.w;
        }
        __syncthreads();
        #pragma unroll 8
        for (int kk = 0; kk < 64; ++kk) {
            float a[4], bb[4];
            *(float4*)a  = *(const float4*)&as[kk][rb];
            *(float4*)bb = *(const float4*)&bs[kk][cb];
            #pragma unroll
            for (int i = 0; i < 4; ++i)
                #pragma unroll
                for (int jj = 0; jj < 4; ++jj)
                    acc[i][jj] += a[i] * bb[jj];
        }
        __syncthreads();
    }
    float4 bo = *(const float4*)&b_out[cb];
    #pragma unroll
    for (int i = 0; i < 4; ++i) {
        float4 o = make_float4(acc[i][0] + bo.x, acc[i][1] + bo.y,
                               acc[i][2] + bo.z, acc[i][3] + bo.w);
        *(float4*)&em[(size_t)(m0 + rb + i) * 64 + cb] = o;
    }
}

// ---------------- K4: CRF numerator + forward algorithm ----------------
__global__ __launch_bounds__(256) void crf_kernel(
    const float* __restrict__ em, const int* __restrict__ tags,
    const float* __restrict__ start_t, const float* __restrict__ end_t,
    const float* __restrict__ trans, float* __restrict__ nll)
{
    const int b = blockIdx.x;
    const int tid = threadIdx.x;
    const int j = tid & 63;
    const int q = tid >> 6;
    __shared__ float s_lds[64];
    __shared__ float part[4][64];
    __shared__ float m_sh, num_sh;
    float tr[16];
    #pragma unroll
    for (int ii = 0; ii < 16; ++ii) tr[ii] = trans[(q * 16 + ii) * 64 + j];
    const float* emb_b = em + (size_t)b * 8192;
    const int* tg_b = tags + b * 128;
    float numpart = 0.f;
    if (tid < 128) {
        int l = tid;
        int tg = tg_b[l];
        numpart = emb_b[l * 64 + tg];
        if (l < 127) numpart += trans[tg * 64 + tg_b[l + 1]];
        if (l == 0)  numpart += start_t[tg];
        if (l == 127) numpart += end_t[tg];
    }
    float red = numpart;
    #pragma unroll
    for (int off = 32; off >= 1; off >>= 1) red += __shfl_xor(red, off);
    if (j == 0) part[q][0] = red;
    if (q == 0) s_lds[j] = start_t[j] + emb_b[j];
    __syncthreads();
    if (tid == 0) num_sh = part[0][0] + part[1][0] + part[2][0] + part[3][0];
    __syncthreads();
    for (int l = 1; l < 128; ++l) {
        if (q == 0) {
            float v = s_lds[j];
            #pragma unroll
            for (int off = 32; off >= 1; off >>= 1) v = fmaxf(v, __shfl_xor(v, off));
            if (j == 0) m_sh = v;
        }
        __syncthreads();
        const float m = m_sh;
        float sv[16];
        #pragma unroll
        for (int t4 = 0; t4 < 4; ++t4) {
            float4 v = *(const float4*)&s_lds[q * 16 + 4 * t4];
            sv[4 * t4] = v.x; sv[4 * t4 + 1] = v.y; sv[4 * t4 + 2] = v.z; sv[4 * t4 + 3] = v.w;
        }
        float acc = 0.f;
        #pragma unroll
        for (int ii = 0; ii < 16; ++ii) acc += __expf(sv[ii] + tr[ii] - m);
        part[q][j] = acc;
        __syncthreads();
        if (q == 0) {
            float t = part[0][j] + part[1][j] + part[2][j] + part[3][j];
            s_lds[j] = m + __logf(t) + emb_b[l * 64 + j];
        }
    }
    if (q == 0) {
        float v = s_lds[j] + end_t[j];
        float mm = v;
        #pragma unroll
        for (int off = 32; off >= 1; off >>= 1) mm = fmaxf(mm, __shfl_xor(mm, off));
        float e = __expf(v - mm);
        #pragma unroll
        for (int off = 32; off >= 1; off >>= 1) e += __shfl_xor(e, off);
        if (j == 0) nll[b] = (mm + __logf(e)) - num_sh;
    }
}

// ---------------- K5: final mean ----------------
__global__ void finalize(const float* __restrict__ nll, float* __restrict__ out)
{
    int j = threadIdx.x;
    float v = nll[j];
    #pragma unroll
    for (int off = 32; off >= 1; off >>= 1) v += __shfl_xor(v, off);
    if (j == 0) out[0] = v * (1.f / 64.f);
}

extern "C" void kernel_launch(void* const* d_in, const int* in_sizes, int n_in,
                              void* d_out, int out_size, void* d_ws, size_t ws_size,
                              hipStream_t stream) {
    const int* sent      = (const int*)d_in[0];
    const int* tags      = (const int*)d_in[1];
    const float* emb     = (const float*)d_in[2];
    const float* w_ih_f  = (const float*)d_in[3];
    const float* w_hh_f  = (const float*)d_in[4];
    const float* b_ih_f  = (const float*)d_in[5];
    const float* b_hh_f  = (const float*)d_in[6];
    const float* w_ih_b  = (const float*)d_in[7];
    const float* w_hh_b  = (const float*)d_in[8];
    const float* b_ih_b  = (const float*)d_in[9];
    const float* b_hh_b  = (const float*)d_in[10];
    const float* w_out   = (const float*)d_in[11];
    const float* b_out   = (const float*)d_in[12];
    const float* start_t = (const float*)d_in[13];
    const float* end_t   = (const float*)d_in[14];
    const float* trans   = (const float*)d_in[15];

    float* ws = (float*)d_ws;
    float* xp        = ws + XP_OFF;
    float* lstm_out  = ws + LSTM_OFF;
    float* em        = ws + EM_OFF;
    unsigned int* w8 = (unsigned int*)(ws + WBF_OFF);
    float* nll       = ws + NLL_OFF;

    cvt_whh_fp8<<<dim3(512), dim3(256), 0, stream>>>(w_hh_f, w_hh_b, w8);
    xp_gemm<<<dim3(64, 16), dim3(256), 0, stream>>>(sent, emb,
        w_ih_f, b_ih_f, b_hh_f, w_ih_b, b_ih_b, b_hh_b, xp);
    lstm_rec<<<dim3(128), dim3(1024), 0, stream>>>(xp, w8, lstm_out);
    emis_gemm<<<dim3(128), dim3(256), 0, stream>>>(lstm_out, w_out, b_out, em);
    crf_kernel<<<dim3(64), dim3(256), 0, stream>>>(em, tags, start_t, end_t, trans, nll);
    finalize<<<dim3(1), dim3(64), 0, stream>>>(nll, (float*)d_out);
}